// Round 9
// baseline (324.278 us; speedup 1.0000x reference)
//
#include <hip/hip_runtime.h>
#include <math.h>

// ---------------------------------------------------------------------------
// SiameseRPN one-branch, round 9 — DISCRIMINATING EXPERIMENT:
//  k_fold: doubled (4608 blocks): blocks 0-2303 compute WFP copy0, blocks
//          2304-4607 recompute identical partials into copy1 (re-reads the
//          302 MB w_template a second time, HBM-cold). k2 combines
//          0.5*((s0+s1)+(s0'+s1')) == s0+s1 bit-exactly.
//          delta(total vs R8) == current fold duration.
//          + __builtin_nontemporal_load on the w_template stream (L3-bypass
//          mechanism test).
//  k0/k_conv/k_cred/k2/k3/k4: unchanged from R8 (except k2 4-slab combine).
// Workspace: 8,067,200 floats = 32.3 MB.
// ---------------------------------------------------------------------------

#define WS_TFP 0            // 591872
#define WS_TP  591872       // 389120  -> 980992
#define WS_BF  980992       // 128     -> 981120
#define WS_WFP 981120       // 2 copies x 2 halves x [128 eh][4608 k] -> +2359296 = 3340416
#define WS_Z2P 3340416      // 401408  -> 3741824
#define WS_MRG 3741824      // 131072  -> 3872896
#define WS_CVP 3872896      // 16*262144 -> 8067200
#define WFP_HALF 589824
#define WFP_FULL 1179648

typedef float f4u __attribute__((ext_vector_type(4), aligned(4)));
typedef float f4a __attribute__((ext_vector_type(4)));   // 16B-aligned

#define FMA4(ww, vv) \
  acc.x = fmaf(ww, (vv).x, acc.x); acc.y = fmaf(ww, (vv).y, acc.y); \
  acc.z = fmaf(ww, (vv).z, acc.z); acc.w = fmaf(ww, (vv).w, acc.w)

#define NTL(p) __builtin_nontemporal_load((const f4a*)(p))

__global__ __launch_bounds__(256) void k_fold(
    const float* __restrict__ wtpl,    // w_template 16384*4608
    const float* __restrict__ wm,      // w_merge_cls 256
    float* ws)
{
  const int bid0 = blockIdx.x;
  const int copy = (bid0 >= 2304) ? 1 : 0;
  const int bid = bid0 - copy * 2304;
  const int g = bid / 18, rest = bid % 18;
  const int chunk = rest >> 1, half = rest & 1;
  const int tid = threadIdx.x;
  const int colv = tid & 127, rowg = tid >> 7;
  const int c0 = chunk * 512 + colv * 4;
  const int row0 = g * 128 + half * 64 + rowg * 32;
  const float* base = wtpl + (size_t)row0 * 4608 + c0;
  const float* wmb = wm + (g & 1) * 128 + half * 64 + rowg * 32;
  f4a acc = {0.f, 0.f, 0.f, 0.f};
  #pragma unroll
  for (int rr = 0; rr < 32; rr += 16) {
    const float* b = base + (size_t)rr * 4608;
    const f4a v0  = NTL(b);
    const f4a v1  = NTL(b + 1 * 4608);
    const f4a v2  = NTL(b + 2 * 4608);
    const f4a v3  = NTL(b + 3 * 4608);
    const f4a v4  = NTL(b + 4 * 4608);
    const f4a v5  = NTL(b + 5 * 4608);
    const f4a v6  = NTL(b + 6 * 4608);
    const f4a v7  = NTL(b + 7 * 4608);
    const f4a v8  = NTL(b + 8 * 4608);
    const f4a v9  = NTL(b + 9 * 4608);
    const f4a v10 = NTL(b + 10 * 4608);
    const f4a v11 = NTL(b + 11 * 4608);
    const f4a v12 = NTL(b + 12 * 4608);
    const f4a v13 = NTL(b + 13 * 4608);
    const f4a v14 = NTL(b + 14 * 4608);
    const f4a v15 = NTL(b + 15 * 4608);
    const float w0 = wmb[rr + 0],  w1 = wmb[rr + 1];
    const float w2 = wmb[rr + 2],  w3 = wmb[rr + 3];
    const float w4 = wmb[rr + 4],  w5 = wmb[rr + 5];
    const float w6 = wmb[rr + 6],  w7 = wmb[rr + 7];
    const float w8 = wmb[rr + 8],  w9 = wmb[rr + 9];
    const float w10 = wmb[rr + 10], w11 = wmb[rr + 11];
    const float w12 = wmb[rr + 12], w13 = wmb[rr + 13];
    const float w14 = wmb[rr + 14], w15 = wmb[rr + 15];
    FMA4(w0, v0);   FMA4(w1, v1);   FMA4(w2, v2);   FMA4(w3, v3);
    FMA4(w4, v4);   FMA4(w5, v5);   FMA4(w6, v6);   FMA4(w7, v7);
    FMA4(w8, v8);   FMA4(w9, v9);   FMA4(w10, v10); FMA4(w11, v11);
    FMA4(w12, v12); FMA4(w13, v13); FMA4(w14, v14); FMA4(w15, v15);
  }
  __shared__ f4a red[128];
  if (rowg) red[colv] = acc;
  __syncthreads();
  if (!rowg) {
    const f4a o = red[colv];
    acc.x += o.x; acc.y += o.y; acc.z += o.z; acc.w += o.w;
    float* wp = ws + WS_WFP + (size_t)copy * WFP_FULL
                            + (size_t)half * WFP_HALF + (size_t)g * 4608;
    *(f4a*)(wp + c0) = acc;
  }
}

__global__ __launch_bounds__(256) void k0_prep(
    const float* __restrict__ tfeat,   // target_feat 512*32*32
    const float* __restrict__ wm,      // w_merge_cls 256
    const float* __restrict__ btpl,    // b_template 16384
    float* ws)
{
  const int N0 = 591872, N2 = 389120;
  const int total = N0 + N2;
  for (int idx = blockIdx.x * 256 + threadIdx.x; idx < total + 128; idx += gridDim.x * 256) {
    if (idx < N0) {
      int ci = idx / 1156, r = idx % 1156;
      int yy = r / 34, xx = r % 34;
      float v = 0.f;
      if (yy >= 1 && yy <= 32 && xx >= 1 && xx <= 32)
        v = tfeat[ci * 1024 + (yy - 1) * 32 + (xx - 1)];
      ws[WS_TFP + idx] = v;
    } else if (idx < total) {
      ws[WS_TP + (idx - N0)] = 0.f;
    } else {
      const int eh = idx - total;
      const int e = eh >> 1, h = eh & 1;
      const float* wmp = wm + h * 128;
      const float* bp = btpl + e * 256 + h * 128;
      float s = 0.f;
      for (int cl = 0; cl < 128; cl++) s = fmaf(wmp[cl], bp[cl], s);
      ws[WS_BF + eh] = s;
    }
  }
}

__global__ __launch_bounds__(256) void k_conv(
    const float* __restrict__ wtgt,    // w_target 256*512*9
    float* ws)
{
  // grid: coblk(16) x pxblk(16) x ks(8); thread: ksub(2) x cog(4) x pxg(32)
  const int bid = blockIdx.x;
  const int coblk = bid >> 7, pxblk = (bid >> 3) & 15, ks = bid & 7;
  const int tid = threadIdx.x;
  const int ksub = tid >> 7, sub = tid & 127;
  const int cog = sub >> 5, pxg = sub & 31;
  const int row = pxg >> 4, x0 = (pxg & 15) * 2;
  const int y = pxblk * 2 + row;
  const int co0 = coblk * 16 + cog * 4;
  const int ci0 = ks * 64 + ksub * 32;
  const float* tfp = ws + WS_TFP;

  float acc[4][2] = {{0.f, 0.f}, {0.f, 0.f}, {0.f, 0.f}, {0.f, 0.f}};
  for (int i = 0; i < 32; i++) {
    const int ci = ci0 + i;
    const float* tin = tfp + (size_t)ci * 1156 + y * 34 + x0;
    const f4u p0 = *(const f4u*)(tin);
    const f4u p1 = *(const f4u*)(tin + 34);
    const f4u p2 = *(const f4u*)(tin + 68);
    #pragma unroll
    for (int c = 0; c < 4; c++) {
      const float* wr = wtgt + (size_t)(co0 + c) * 4608 + ci * 9;
      const f4u wa = *(const f4u*)(wr);
      const f4u wb = *(const f4u*)(wr + 4);
      const float w8 = wr[8];
      acc[c][0] += wa.x * p0.x + wa.y * p0.y + wa.z * p0.z
                 + wa.w * p1.x + wb.x * p1.y + wb.y * p1.z
                 + wb.z * p2.x + wb.w * p2.y + w8 * p2.z;
      acc[c][1] += wa.x * p0.y + wa.y * p0.z + wa.z * p0.w
                 + wa.w * p1.y + wb.x * p1.z + wb.y * p1.w
                 + wb.z * p2.y + wb.w * p2.z + w8 * p2.w;
    }
  }
  float* cvp = ws + WS_CVP + (size_t)(ks * 2 + ksub) * 262144;
  #pragma unroll
  for (int c = 0; c < 4; c++) {
    cvp[(co0 + c) * 1024 + y * 32 + x0 + 0] = acc[c][0];
    cvp[(co0 + c) * 1024 + y * 32 + x0 + 1] = acc[c][1];
  }
}

__global__ __launch_bounds__(256) void k_cred(
    const float* __restrict__ btgt,
    const float* __restrict__ gamma, const float* __restrict__ beta,
    const float* __restrict__ mean, const float* __restrict__ var,
    float* ws)
{
  const int co = blockIdx.x;
  const int tid = threadIdx.x;
  const float sc = gamma[co] * rsqrtf(var[co] + 1e-5f);
  const float off = btgt[co] - mean[co];
  const float bt = beta[co];
  const float* cvp = ws + WS_CVP + (size_t)co * 1024;
  float* tP = ws + WS_TP;
  #pragma unroll
  for (int k = 0; k < 4; k++) {
    const int j = k * 256 + tid;
    float s = 0.f;
    #pragma unroll
    for (int sl = 0; sl < 16; sl++) s += cvp[(size_t)sl * 262144 + j];
    const float t = ((s + off) * sc + bt) * 0.1f;
    const int yy = j >> 5, xx = j & 31;
    tP[co * 1520 + (yy + 3) * 40 + (xx + 3)] = t;
  }
}

__global__ __launch_bounds__(256) void k2_z2(
    const float* __restrict__ zfeat,    // template_feat 2*512*49
    float* ws)
{
  __shared__ float Tl[50][144];
  const int tid = threadIdx.x;
  const int n = blockIdx.x >> 5, kc = blockIdx.x & 31;
  const int ci0 = kc * 16;
  for (int idx = tid; idx < 7200; idx += 256) {
    const int uv = idx / 144, kk = idx % 144;
    float v = 0.f;
    if (uv < 49) {
      const int u = uv / 7, vv = uv % 7;
      const int ci = ci0 + kk / 9, pq = kk % 9;
      const int p = pq / 3, q = pq % 3;
      const int yy = u + p - 1, xx = vv + q - 1;
      if (yy >= 0 && yy < 7 && xx >= 0 && xx < 7)
        v = zfeat[n * 25088 + ci * 49 + yy * 7 + xx];
    }
    Tl[uv][kk] = v;
  }
  __syncthreads();
  const int ehq = tid & 31, uvg = tid >> 5;
  const int eh0 = ehq * 4;
  const int uv0 = (uvg == 0) ? 0 : uvg * 6 + 1;
  const float* wfp = ws + WS_WFP;
  float4 acc[7];
  #pragma unroll
  for (int i = 0; i < 7; i++) acc[i] = make_float4(0.f, 0.f, 0.f, 0.f);
  for (int g = 0; g < 36; g++) {
    const int koff = ci0 * 9 + g * 4;
    // wvE[e] = 0.5*((s0+s1) + (s0'+s1')) == (s0+s1) bit-exactly (s'==s)
    f4a wvE[4];
    #pragma unroll
    for (int e = 0; e < 4; e++) {
      const float* pe = wfp + (size_t)(eh0 + e) * 4608 + koff;
      f4a a = *(const f4a*)(pe);
      a += *(const f4a*)(pe + WFP_HALF);
      f4a b2 = *(const f4a*)(pe + WFP_FULL);
      b2 += *(const f4a*)(pe + WFP_FULL + WFP_HALF);
      wvE[e] = 0.5f * (a + b2);
    }
    #pragma unroll
    for (int uu = 0; uu < 7; uu++) {
      const float4 t4 = *(const float4*)(&Tl[uv0 + uu][g * 4]);
      acc[uu].x = fmaf(t4.x, wvE[0].x, fmaf(t4.y, wvE[0].y, fmaf(t4.z, wvE[0].z, fmaf(t4.w, wvE[0].w, acc[uu].x))));
      acc[uu].y = fmaf(t4.x, wvE[1].x, fmaf(t4.y, wvE[1].y, fmaf(t4.z, wvE[1].z, fmaf(t4.w, wvE[1].w, acc[uu].y))));
      acc[uu].z = fmaf(t4.x, wvE[2].x, fmaf(t4.y, wvE[2].y, fmaf(t4.z, wvE[2].z, fmaf(t4.w, wvE[2].w, acc[uu].z))));
      acc[uu].w = fmaf(t4.x, wvE[3].x, fmaf(t4.y, wvE[3].y, fmaf(t4.z, wvE[3].z, fmaf(t4.w, wvE[3].w, acc[uu].w))));
    }
  }
  float* z2p = ws + WS_Z2P;
  #pragma unroll
  for (int uu = 0; uu < 7; uu++) {
    const int uv = uv0 + uu;
    if (uv <= 48)
      *(float4*)(z2p + ((size_t)((n * 32 + kc) * 49 + uv)) * 128 + eh0) = acc[uu];
  }
}

__global__ __launch_bounds__(128) void k3_merged(float* ws)
{
  __shared__ float Z2s[16][7][8];
  const int tid = threadIdx.x;
  const int bid = blockIdx.x;
  const int n = bid >> 7, rest = bid & 127;
  const int ec = rest >> 4, hq = rest & 15;
  const int c0 = ec * 16, h0 = hq * 2;
  const float* z2p = ws + WS_Z2P;
  const float* bf = ws + WS_BF;
  for (int idx = tid; idx < 784; idx += 128) {
    const int cl = idx & 15, uv = idx >> 4;
    float s = bf[c0 + cl];
    const float* p = z2p + (size_t)(n * 1568 + uv) * 128 + (c0 + cl);
    #pragma unroll 8
    for (int kc = 0; kc < 32; kc++) s += p[(size_t)kc * 6272];
    Z2s[cl][uv / 7][uv % 7] = s;
  }
  for (int idx = tid; idx < 112; idx += 128)
    Z2s[idx / 7][idx % 7][7] = 0.f;
  __syncthreads();

  const int e = tid >> 4, row = (tid >> 3) & 1, wq = tid & 7;
  const int w0 = wq * 4;
  const float* tP = ws + WS_TP;
  float acc[4] = {0.f, 0.f, 0.f, 0.f};
  #pragma unroll
  for (int h128 = 0; h128 < 2; h128++) {
    const int cl = 2 * e + h128;
    const float* tc = tP + (size_t)(128 * n + c0 + cl) * 1520;
    #pragma unroll
    for (int u = 0; u < 7; u++) {
      const float* trow = tc + (h0 + row + u) * 40 + w0;
      float tw[12];
      *(float4*)&tw[0] = *(const float4*)(trow);
      *(float4*)&tw[4] = *(const float4*)(trow + 4);
      *(float4*)&tw[8] = *(const float4*)(trow + 8);
      float z[8];
      *(float4*)&z[0] = *(const float4*)&Z2s[cl][u][0];
      *(float4*)&z[4] = *(const float4*)&Z2s[cl][u][4];
      #pragma unroll
      for (int px = 0; px < 4; px++)
        #pragma unroll
        for (int v = 0; v < 8; v++)
          acc[px] = fmaf(z[v], tw[px + v], acc[px]);
    }
  }
  float* mrg = ws + WS_MRG;
  *(float4*)(mrg + (size_t)(((n * 64 + ec * 8 + e) * 32) + h0 + row) * 32 + w0) =
      make_float4(acc[0], acc[1], acc[2], acc[3]);
}

__global__ __launch_bounds__(256) void k4_heads(
    const float* __restrict__ cb,
    const float* __restrict__ wcls, const float* __restrict__ bcls,
    const float* __restrict__ wbox, const float* __restrict__ bbox,
    float* ws, float* __restrict__ out)
{
  __shared__ float mrg_l[32][66];
  __shared__ float wcb_l[54][64];
  __shared__ float bias_l[54];
  __shared__ float logits[18][32];
  const int tid = threadIdx.x;
  const int n = blockIdx.x >> 5, h = blockIdx.x & 31;
  const float* mrg = ws + WS_MRG;
  for (int idx = tid; idx < 2048; idx += 256) {
    const int e = idx >> 5, w = idx & 31;
    mrg_l[w][e] = mrg[(size_t)(((n * 64 + e) * 32) + h) * 32 + w] + cb[e];
  }
  for (int idx = tid; idx < 3456; idx += 256) {
    const int ch = idx >> 6, e = idx & 63;
    wcb_l[ch][e] = (ch < 18) ? wcls[ch * 64 + e] : wbox[(ch - 18) * 64 + e];
  }
  if (tid < 54) bias_l[tid] = (tid < 18) ? bcls[tid] : bbox[tid - 18];
  __syncthreads();

  const int w = tid & 31, chg = tid >> 5;
  const int cnt = (chg < 6) ? 7 : 6;
  float acc[7] = {0.f, 0.f, 0.f, 0.f, 0.f, 0.f, 0.f};
  for (int e2 = 0; e2 < 32; e2++) {
    const float2 m2 = *(const float2*)&mrg_l[w][e2 * 2];
    #pragma unroll
    for (int i = 0; i < 7; i++) {
      if (i < cnt) {
        const int ch = chg + 8 * i;
        const float2 wv = *(const float2*)&wcb_l[ch][e2 * 2];
        acc[i] = fmaf(m2.x, wv.x, acc[i]);
        acc[i] = fmaf(m2.y, wv.y, acc[i]);
      }
    }
  }
  #pragma unroll
  for (int i = 0; i < 7; i++) {
    if (i < cnt) {
      const int ch = chg + 8 * i;
      const float v = acc[i] + bias_l[ch];
      if (ch < 18) logits[ch][w] = v;
      else out[36864 + n * 36864 + (ch - 18) * 1024 + h * 32 + w] = v;
    }
  }
  __syncthreads();
  for (int idx = tid; idx < 576; idx += 256) {
    const int ch = idx >> 5, w2 = idx & 31;
    const float a = logits[ch][w2];
    const float b = logits[(ch + 9) % 18][w2];
    const float m = fmaxf(a, b);
    const float ea = expf(a - m), eb = expf(b - m);
    out[n * 18432 + ch * 1024 + h * 32 + w2] = ea / (ea + eb);
  }
}

extern "C" void kernel_launch(void* const* d_in, const int* in_sizes, int n_in,
                              void* d_out, int out_size, void* d_ws, size_t ws_size,
                              hipStream_t stream) {
  (void)in_sizes; (void)n_in; (void)out_size; (void)ws_size;
  const float* target_feat   = (const float*)d_in[0];
  const float* template_feat = (const float*)d_in[1];
  const float* w_target      = (const float*)d_in[2];
  const float* b_target      = (const float*)d_in[3];
  const float* bn_gamma      = (const float*)d_in[4];
  const float* bn_beta       = (const float*)d_in[5];
  const float* bn_mean       = (const float*)d_in[6];
  const float* bn_var        = (const float*)d_in[7];
  const float* w_template    = (const float*)d_in[8];
  const float* b_template    = (const float*)d_in[9];
  const float* w_merge       = (const float*)d_in[10];
  const float* corr_bias     = (const float*)d_in[11];
  const float* w_cls         = (const float*)d_in[12];
  const float* b_cls         = (const float*)d_in[13];
  const float* w_box         = (const float*)d_in[14];
  const float* b_box         = (const float*)d_in[15];
  float* ws = (float*)d_ws;
  float* out = (float*)d_out;

  hipLaunchKernelGGL(k_fold, dim3(4608), dim3(256), 0, stream,
                     w_template, w_merge, ws);
  hipLaunchKernelGGL(k0_prep, dim3(2048), dim3(256), 0, stream,
                     target_feat, w_merge, b_template, ws);
  hipLaunchKernelGGL(k_conv, dim3(2048), dim3(256), 0, stream,
                     w_target, ws);
  hipLaunchKernelGGL(k_cred, dim3(256), dim3(256), 0, stream,
                     b_target, bn_gamma, bn_beta, bn_mean, bn_var, ws);
  hipLaunchKernelGGL(k2_z2, dim3(64), dim3(256), 0, stream,
                     template_feat, ws);
  hipLaunchKernelGGL(k3_merged, dim3(256), dim3(128), 0, stream, ws);
  hipLaunchKernelGGL(k4_heads, dim3(64), dim3(256), 0, stream,
                     corr_bias, w_cls, b_cls, w_box, b_box, ws, out);
}

// Round 10
// 273.008 us; speedup vs baseline: 1.1878x; 1.1878x over previous
//
#include <hip/hip_runtime.h>
#include <math.h>

// ---------------------------------------------------------------------------
// SiameseRPN one-branch, round 10 — DRAM-streaming fold:
//  k_fold: 512 blocks; block (g,sub) owns 32 CONTIGUOUS rows of w_template
//          (590 KB span), walked linearly with coalesced nt float4 loads.
//          Thread t accumulates cols {t*4 + 1024*s} (5 f4 accs) over rows.
//          Partials -> WFP[sub][128 g][4608]. Fixes the 18.4KB-stride DRAM
//          row-thrash that capped all previous folds at ~1.7-2.2 TB/s.
//  k2    : sums the 4 row-sub slabs on load.
//  k0/k_conv/k_cred/k3/k4: unchanged from R9.
// Workspace: 8,067,200 floats = 32.3 MB (offsets identical to R9).
// ---------------------------------------------------------------------------

#define WS_TFP 0            // 591872
#define WS_TP  591872       // 389120  -> 980992
#define WS_BF  980992       // 128     -> 981120
#define WS_WFP 981120       // 4 slabs x [128][4608] = 2359296 -> 3340416
#define WS_Z2P 3340416      // 401408  -> 3741824
#define WS_MRG 3741824      // 131072  -> 3872896
#define WS_CVP 3872896      // 16*262144 -> 8067200
#define WFP_SLAB 589824

typedef float f4u __attribute__((ext_vector_type(4), aligned(4)));
typedef float f4a __attribute__((ext_vector_type(4)));   // 16B-aligned

#define FMA4A(accv, ww, vv) \
  accv.x = fmaf(ww, (vv).x, accv.x); accv.y = fmaf(ww, (vv).y, accv.y); \
  accv.z = fmaf(ww, (vv).z, accv.z); accv.w = fmaf(ww, (vv).w, accv.w)

#define NTL(p) __builtin_nontemporal_load((const f4a*)(p))

__global__ __launch_bounds__(256) void k_fold(
    const float* __restrict__ wtpl,    // w_template 16384*4608
    const float* __restrict__ wm,      // w_merge_cls 256
    float* ws)
{
  // block: g in [0,128) (eh group), sub in [0,4) (32-row contiguous window)
  const int g = blockIdx.x >> 2, sub = blockIdx.x & 3;
  const int tid = threadIdx.x;
  __shared__ float wS[32];
  if (tid < 32) wS[tid] = wm[(g & 1) * 128 + sub * 32 + tid];
  __syncthreads();
  const float* base = wtpl + (size_t)(g * 128 + sub * 32) * 4608;
  const int c0 = tid * 4;
  const int c4 = 4096 + (tid & 127) * 4;
  const bool tail = (tid < 128);
  f4a a0 = {0.f, 0.f, 0.f, 0.f}, a1 = a0, a2 = a0, a3 = a0, a4 = a0;
  #pragma unroll 2
  for (int r = 0; r < 32; r++) {
    const float* row = base + (size_t)r * 4608;
    const f4a v0 = NTL(row + c0);
    const f4a v1 = NTL(row + c0 + 1024);
    const f4a v2 = NTL(row + c0 + 2048);
    const f4a v3 = NTL(row + c0 + 3072);
    f4a v4 = {0.f, 0.f, 0.f, 0.f};
    if (tail) v4 = NTL(row + c4);
    const float w = wS[r];
    FMA4A(a0, w, v0); FMA4A(a1, w, v1); FMA4A(a2, w, v2);
    FMA4A(a3, w, v3); FMA4A(a4, w, v4);
  }
  float* wp = ws + WS_WFP + (size_t)sub * WFP_SLAB + (size_t)g * 4608;
  *(f4a*)(wp + c0) = a0;
  *(f4a*)(wp + c0 + 1024) = a1;
  *(f4a*)(wp + c0 + 2048) = a2;
  *(f4a*)(wp + c0 + 3072) = a3;
  if (tail) *(f4a*)(wp + c4) = a4;
}

__global__ __launch_bounds__(256) void k0_prep(
    const float* __restrict__ tfeat,   // target_feat 512*32*32
    const float* __restrict__ wm,      // w_merge_cls 256
    const float* __restrict__ btpl,    // b_template 16384
    float* ws)
{
  const int N0 = 591872, N2 = 389120;
  const int total = N0 + N2;
  for (int idx = blockIdx.x * 256 + threadIdx.x; idx < total + 128; idx += gridDim.x * 256) {
    if (idx < N0) {
      int ci = idx / 1156, r = idx % 1156;
      int yy = r / 34, xx = r % 34;
      float v = 0.f;
      if (yy >= 1 && yy <= 32 && xx >= 1 && xx <= 32)
        v = tfeat[ci * 1024 + (yy - 1) * 32 + (xx - 1)];
      ws[WS_TFP + idx] = v;
    } else if (idx < total) {
      ws[WS_TP + (idx - N0)] = 0.f;
    } else {
      const int eh = idx - total;
      const int e = eh >> 1, h = eh & 1;
      const float* wmp = wm + h * 128;
      const float* bp = btpl + e * 256 + h * 128;
      float s = 0.f;
      for (int cl = 0; cl < 128; cl++) s = fmaf(wmp[cl], bp[cl], s);
      ws[WS_BF + eh] = s;
    }
  }
}

__global__ __launch_bounds__(256) void k_conv(
    const float* __restrict__ wtgt,    // w_target 256*512*9
    float* ws)
{
  // grid: coblk(16) x pxblk(16) x ks(8); thread: ksub(2) x cog(4) x pxg(32)
  const int bid = blockIdx.x;
  const int coblk = bid >> 7, pxblk = (bid >> 3) & 15, ks = bid & 7;
  const int tid = threadIdx.x;
  const int ksub = tid >> 7, sub = tid & 127;
  const int cog = sub >> 5, pxg = sub & 31;
  const int row = pxg >> 4, x0 = (pxg & 15) * 2;
  const int y = pxblk * 2 + row;
  const int co0 = coblk * 16 + cog * 4;
  const int ci0 = ks * 64 + ksub * 32;
  const float* tfp = ws + WS_TFP;

  float acc[4][2] = {{0.f, 0.f}, {0.f, 0.f}, {0.f, 0.f}, {0.f, 0.f}};
  for (int i = 0; i < 32; i++) {
    const int ci = ci0 + i;
    const float* tin = tfp + (size_t)ci * 1156 + y * 34 + x0;
    const f4u p0 = *(const f4u*)(tin);
    const f4u p1 = *(const f4u*)(tin + 34);
    const f4u p2 = *(const f4u*)(tin + 68);
    #pragma unroll
    for (int c = 0; c < 4; c++) {
      const float* wr = wtgt + (size_t)(co0 + c) * 4608 + ci * 9;
      const f4u wa = *(const f4u*)(wr);
      const f4u wb = *(const f4u*)(wr + 4);
      const float w8 = wr[8];
      acc[c][0] += wa.x * p0.x + wa.y * p0.y + wa.z * p0.z
                 + wa.w * p1.x + wb.x * p1.y + wb.y * p1.z
                 + wb.z * p2.x + wb.w * p2.y + w8 * p2.z;
      acc[c][1] += wa.x * p0.y + wa.y * p0.z + wa.z * p0.w
                 + wa.w * p1.y + wb.x * p1.z + wb.y * p1.w
                 + wb.z * p2.y + wb.w * p2.z + w8 * p2.w;
    }
  }
  float* cvp = ws + WS_CVP + (size_t)(ks * 2 + ksub) * 262144;
  #pragma unroll
  for (int c = 0; c < 4; c++) {
    cvp[(co0 + c) * 1024 + y * 32 + x0 + 0] = acc[c][0];
    cvp[(co0 + c) * 1024 + y * 32 + x0 + 1] = acc[c][1];
  }
}

__global__ __launch_bounds__(256) void k_cred(
    const float* __restrict__ btgt,
    const float* __restrict__ gamma, const float* __restrict__ beta,
    const float* __restrict__ mean, const float* __restrict__ var,
    float* ws)
{
  const int co = blockIdx.x;
  const int tid = threadIdx.x;
  const float sc = gamma[co] * rsqrtf(var[co] + 1e-5f);
  const float off = btgt[co] - mean[co];
  const float bt = beta[co];
  const float* cvp = ws + WS_CVP + (size_t)co * 1024;
  float* tP = ws + WS_TP;
  #pragma unroll
  for (int k = 0; k < 4; k++) {
    const int j = k * 256 + tid;
    float s = 0.f;
    #pragma unroll
    for (int sl = 0; sl < 16; sl++) s += cvp[(size_t)sl * 262144 + j];
    const float t = ((s + off) * sc + bt) * 0.1f;
    const int yy = j >> 5, xx = j & 31;
    tP[co * 1520 + (yy + 3) * 40 + (xx + 3)] = t;
  }
}

__global__ __launch_bounds__(256) void k2_z2(
    const float* __restrict__ zfeat,    // template_feat 2*512*49
    float* ws)
{
  __shared__ float Tl[50][144];
  const int tid = threadIdx.x;
  const int n = blockIdx.x >> 5, kc = blockIdx.x & 31;
  const int ci0 = kc * 16;
  for (int idx = tid; idx < 7200; idx += 256) {
    const int uv = idx / 144, kk = idx % 144;
    float v = 0.f;
    if (uv < 49) {
      const int u = uv / 7, vv = uv % 7;
      const int ci = ci0 + kk / 9, pq = kk % 9;
      const int p = pq / 3, q = pq % 3;
      const int yy = u + p - 1, xx = vv + q - 1;
      if (yy >= 0 && yy < 7 && xx >= 0 && xx < 7)
        v = zfeat[n * 25088 + ci * 49 + yy * 7 + xx];
    }
    Tl[uv][kk] = v;
  }
  __syncthreads();
  const int ehq = tid & 31, uvg = tid >> 5;
  const int eh0 = ehq * 4;
  const int uv0 = (uvg == 0) ? 0 : uvg * 6 + 1;
  const float* wfp = ws + WS_WFP;
  float4 acc[7];
  #pragma unroll
  for (int i = 0; i < 7; i++) acc[i] = make_float4(0.f, 0.f, 0.f, 0.f);
  for (int g = 0; g < 36; g++) {
    const int koff = ci0 * 9 + g * 4;
    // wvE[e] = (slab0+slab1) + (slab2+slab3)  (4 row-sub partials)
    f4a wvE[4];
    #pragma unroll
    for (int e = 0; e < 4; e++) {
      const float* pe = wfp + (size_t)(eh0 + e) * 4608 + koff;
      f4a a = *(const f4a*)(pe);
      a += *(const f4a*)(pe + WFP_SLAB);
      f4a b2 = *(const f4a*)(pe + 2 * WFP_SLAB);
      b2 += *(const f4a*)(pe + 3 * WFP_SLAB);
      wvE[e] = a + b2;
    }
    #pragma unroll
    for (int uu = 0; uu < 7; uu++) {
      const float4 t4 = *(const float4*)(&Tl[uv0 + uu][g * 4]);
      acc[uu].x = fmaf(t4.x, wvE[0].x, fmaf(t4.y, wvE[0].y, fmaf(t4.z, wvE[0].z, fmaf(t4.w, wvE[0].w, acc[uu].x))));
      acc[uu].y = fmaf(t4.x, wvE[1].x, fmaf(t4.y, wvE[1].y, fmaf(t4.z, wvE[1].z, fmaf(t4.w, wvE[1].w, acc[uu].y))));
      acc[uu].z = fmaf(t4.x, wvE[2].x, fmaf(t4.y, wvE[2].y, fmaf(t4.z, wvE[2].z, fmaf(t4.w, wvE[2].w, acc[uu].z))));
      acc[uu].w = fmaf(t4.x, wvE[3].x, fmaf(t4.y, wvE[3].y, fmaf(t4.z, wvE[3].z, fmaf(t4.w, wvE[3].w, acc[uu].w))));
    }
  }
  float* z2p = ws + WS_Z2P;
  #pragma unroll
  for (int uu = 0; uu < 7; uu++) {
    const int uv = uv0 + uu;
    if (uv <= 48)
      *(float4*)(z2p + ((size_t)((n * 32 + kc) * 49 + uv)) * 128 + eh0) = acc[uu];
  }
}

__global__ __launch_bounds__(128) void k3_merged(float* ws)
{
  __shared__ float Z2s[16][7][8];
  const int tid = threadIdx.x;
  const int bid = blockIdx.x;
  const int n = bid >> 7, rest = bid & 127;
  const int ec = rest >> 4, hq = rest & 15;
  const int c0 = ec * 16, h0 = hq * 2;
  const float* z2p = ws + WS_Z2P;
  const float* bf = ws + WS_BF;
  for (int idx = tid; idx < 784; idx += 128) {
    const int cl = idx & 15, uv = idx >> 4;
    float s = bf[c0 + cl];
    const float* p = z2p + (size_t)(n * 1568 + uv) * 128 + (c0 + cl);
    #pragma unroll 8
    for (int kc = 0; kc < 32; kc++) s += p[(size_t)kc * 6272];
    Z2s[cl][uv / 7][uv % 7] = s;
  }
  for (int idx = tid; idx < 112; idx += 128)
    Z2s[idx / 7][idx % 7][7] = 0.f;
  __syncthreads();

  const int e = tid >> 4, row = (tid >> 3) & 1, wq = tid & 7;
  const int w0 = wq * 4;
  const float* tP = ws + WS_TP;
  float acc[4] = {0.f, 0.f, 0.f, 0.f};
  #pragma unroll
  for (int h128 = 0; h128 < 2; h128++) {
    const int cl = 2 * e + h128;
    const float* tc = tP + (size_t)(128 * n + c0 + cl) * 1520;
    #pragma unroll
    for (int u = 0; u < 7; u++) {
      const float* trow = tc + (h0 + row + u) * 40 + w0;
      float tw[12];
      *(float4*)&tw[0] = *(const float4*)(trow);
      *(float4*)&tw[4] = *(const float4*)(trow + 4);
      *(float4*)&tw[8] = *(const float4*)(trow + 8);
      float z[8];
      *(float4*)&z[0] = *(const float4*)&Z2s[cl][u][0];
      *(float4*)&z[4] = *(const float4*)&Z2s[cl][u][4];
      #pragma unroll
      for (int px = 0; px < 4; px++)
        #pragma unroll
        for (int v = 0; v < 8; v++)
          acc[px] = fmaf(z[v], tw[px + v], acc[px]);
    }
  }
  float* mrg = ws + WS_MRG;
  *(float4*)(mrg + (size_t)(((n * 64 + ec * 8 + e) * 32) + h0 + row) * 32 + w0) =
      make_float4(acc[0], acc[1], acc[2], acc[3]);
}

__global__ __launch_bounds__(256) void k4_heads(
    const float* __restrict__ cb,
    const float* __restrict__ wcls, const float* __restrict__ bcls,
    const float* __restrict__ wbox, const float* __restrict__ bbox,
    float* ws, float* __restrict__ out)
{
  __shared__ float mrg_l[32][66];
  __shared__ float wcb_l[54][64];
  __shared__ float bias_l[54];
  __shared__ float logits[18][32];
  const int tid = threadIdx.x;
  const int n = blockIdx.x >> 5, h = blockIdx.x & 31;
  const float* mrg = ws + WS_MRG;
  for (int idx = tid; idx < 2048; idx += 256) {
    const int e = idx >> 5, w = idx & 31;
    mrg_l[w][e] = mrg[(size_t)(((n * 64 + e) * 32) + h) * 32 + w] + cb[e];
  }
  for (int idx = tid; idx < 3456; idx += 256) {
    const int ch = idx >> 6, e = idx & 63;
    wcb_l[ch][e] = (ch < 18) ? wcls[ch * 64 + e] : wbox[(ch - 18) * 64 + e];
  }
  if (tid < 54) bias_l[tid] = (tid < 18) ? bcls[tid] : bbox[tid - 18];
  __syncthreads();

  const int w = tid & 31, chg = tid >> 5;
  const int cnt = (chg < 6) ? 7 : 6;
  float acc[7] = {0.f, 0.f, 0.f, 0.f, 0.f, 0.f, 0.f};
  for (int e2 = 0; e2 < 32; e2++) {
    const float2 m2 = *(const float2*)&mrg_l[w][e2 * 2];
    #pragma unroll
    for (int i = 0; i < 7; i++) {
      if (i < cnt) {
        const int ch = chg + 8 * i;
        const float2 wv = *(const float2*)&wcb_l[ch][e2 * 2];
        acc[i] = fmaf(m2.x, wv.x, acc[i]);
        acc[i] = fmaf(m2.y, wv.y, acc[i]);
      }
    }
  }
  #pragma unroll
  for (int i = 0; i < 7; i++) {
    if (i < cnt) {
      const int ch = chg + 8 * i;
      const float v = acc[i] + bias_l[ch];
      if (ch < 18) logits[ch][w] = v;
      else out[36864 + n * 36864 + (ch - 18) * 1024 + h * 32 + w] = v;
    }
  }
  __syncthreads();
  for (int idx = tid; idx < 576; idx += 256) {
    const int ch = idx >> 5, w2 = idx & 31;
    const float a = logits[ch][w2];
    const float b = logits[(ch + 9) % 18][w2];
    const float m = fmaxf(a, b);
    const float ea = expf(a - m), eb = expf(b - m);
    out[n * 18432 + ch * 1024 + h * 32 + w2] = ea / (ea + eb);
  }
}

extern "C" void kernel_launch(void* const* d_in, const int* in_sizes, int n_in,
                              void* d_out, int out_size, void* d_ws, size_t ws_size,
                              hipStream_t stream) {
  (void)in_sizes; (void)n_in; (void)out_size; (void)ws_size;
  const float* target_feat   = (const float*)d_in[0];
  const float* template_feat = (const float*)d_in[1];
  const float* w_target      = (const float*)d_in[2];
  const float* b_target      = (const float*)d_in[3];
  const float* bn_gamma      = (const float*)d_in[4];
  const float* bn_beta       = (const float*)d_in[5];
  const float* bn_mean       = (const float*)d_in[6];
  const float* bn_var        = (const float*)d_in[7];
  const float* w_template    = (const float*)d_in[8];
  const float* b_template    = (const float*)d_in[9];
  const float* w_merge       = (const float*)d_in[10];
  const float* corr_bias     = (const float*)d_in[11];
  const float* w_cls         = (const float*)d_in[12];
  const float* b_cls         = (const float*)d_in[13];
  const float* w_box         = (const float*)d_in[14];
  const float* b_box         = (const float*)d_in[15];
  float* ws = (float*)d_ws;
  float* out = (float*)d_out;

  hipLaunchKernelGGL(k_fold, dim3(512), dim3(256), 0, stream,
                     w_template, w_merge, ws);
  hipLaunchKernelGGL(k0_prep, dim3(2048), dim3(256), 0, stream,
                     target_feat, w_merge, b_template, ws);
  hipLaunchKernelGGL(k_conv, dim3(2048), dim3(256), 0, stream,
                     w_target, ws);
  hipLaunchKernelGGL(k_cred, dim3(256), dim3(256), 0, stream,
                     b_target, bn_gamma, bn_beta, bn_mean, bn_var, ws);
  hipLaunchKernelGGL(k2_z2, dim3(64), dim3(256), 0, stream,
                     template_feat, ws);
  hipLaunchKernelGGL(k3_merged, dim3(256), dim3(128), 0, stream, ws);
  hipLaunchKernelGGL(k4_heads, dim3(64), dim3(256), 0, stream,
                     corr_bias, w_cls, b_cls, w_box, b_box, ws, out);
}

// Round 11
// 235.563 us; speedup vs baseline: 1.3766x; 1.1590x over previous
//
#include <hip/hip_runtime.h>
#include <math.h>

// ---------------------------------------------------------------------------
// SiameseRPN one-branch, round 11 — overlap conv under the fold:
//  k0 : pad target_feat -> tfp[512][34][34]; zero tP[256][38][40]; Bfold.
//  K1 : bid<2304: fold (R8-exact: strided 16-deep float4, NO nt, coalesced
//       stores -> WFP[2][128][4608]) ~45us HBM-roofline;
//       bid>=2304: conv partials K-split x16 -> CVP (VALU, hidden under fold).
//  K2 : bid<256: cred (sum CVP + BN + 0.1 -> tP); bid>=256: z2 partials.
//  k3 : merged = sum t' * Z2.   k4: heads + softmax.
// 5 launches. Workspace: 6,887,552 floats = 27.6 MB (R8 offsets).
// ---------------------------------------------------------------------------

#define WS_TFP 0            // 591872
#define WS_TP  591872       // 389120  -> 980992
#define WS_BF  980992       // 128     -> 981120
#define WS_WFP 981120       // 2*589824 -> 2160768   layout: [half][eh][4608]
#define WS_Z2P 2160768      // 401408  -> 2562176
#define WS_MRG 2562176      // 131072  -> 2693248
#define WS_CVP 2693248      // 16*262144 -> 6887552
#define WFP_HALF 589824

typedef float f4u __attribute__((ext_vector_type(4), aligned(4)));
typedef float f4a __attribute__((ext_vector_type(4)));

#define FMA4(ww, vv) \
  acc.x = fmaf(ww, (vv).x, acc.x); acc.y = fmaf(ww, (vv).y, acc.y); \
  acc.z = fmaf(ww, (vv).z, acc.z); acc.w = fmaf(ww, (vv).w, acc.w)

__global__ __launch_bounds__(256) void k0_prep(
    const float* __restrict__ tfeat,   // target_feat 512*32*32
    const float* __restrict__ wm,      // w_merge_cls 256
    const float* __restrict__ btpl,    // b_template 16384
    float* ws)
{
  const int N0 = 591872, N2 = 389120;
  const int total = N0 + N2;
  for (int idx = blockIdx.x * 256 + threadIdx.x; idx < total + 128; idx += gridDim.x * 256) {
    if (idx < N0) {
      int ci = idx / 1156, r = idx % 1156;
      int yy = r / 34, xx = r % 34;
      float v = 0.f;
      if (yy >= 1 && yy <= 32 && xx >= 1 && xx <= 32)
        v = tfeat[ci * 1024 + (yy - 1) * 32 + (xx - 1)];
      ws[WS_TFP + idx] = v;
    } else if (idx < total) {
      ws[WS_TP + (idx - N0)] = 0.f;
    } else {
      const int eh = idx - total;
      const int e = eh >> 1, h = eh & 1;
      const float* wmp = wm + h * 128;
      const float* bp = btpl + e * 256 + h * 128;
      float s = 0.f;
      for (int cl = 0; cl < 128; cl++) s = fmaf(wmp[cl], bp[cl], s);
      ws[WS_BF + eh] = s;
    }
  }
}

__global__ __launch_bounds__(256) void K1_fold_conv(
    const float* __restrict__ wtpl,    // w_template 16384*4608
    const float* __restrict__ wm,      // w_merge_cls 256
    const float* __restrict__ wtgt,    // w_target 256*512*9
    float* ws)
{
  const int bid0 = blockIdx.x;
  const int tid = threadIdx.x;
  if (bid0 < 2304) {
    // ---------------- FOLD (R8-exact, HBM-roofline) ----------------
    const int bid = bid0;
    const int g = bid / 18, rest = bid % 18;
    const int chunk = rest >> 1, half = rest & 1;
    const int colv = tid & 127, rowg = tid >> 7;
    const int c0 = chunk * 512 + colv * 4;
    const int row0 = g * 128 + half * 64 + rowg * 32;
    const float* base = wtpl + (size_t)row0 * 4608 + c0;
    const float* wmb = wm + (g & 1) * 128 + half * 64 + rowg * 32;
    f4a acc = {0.f, 0.f, 0.f, 0.f};
    #pragma unroll
    for (int rr = 0; rr < 32; rr += 16) {
      const float* b = base + (size_t)rr * 4608;
      const f4a v0  = *(const f4a*)(b);
      const f4a v1  = *(const f4a*)(b + 1 * 4608);
      const f4a v2  = *(const f4a*)(b + 2 * 4608);
      const f4a v3  = *(const f4a*)(b + 3 * 4608);
      const f4a v4  = *(const f4a*)(b + 4 * 4608);
      const f4a v5  = *(const f4a*)(b + 5 * 4608);
      const f4a v6  = *(const f4a*)(b + 6 * 4608);
      const f4a v7  = *(const f4a*)(b + 7 * 4608);
      const f4a v8  = *(const f4a*)(b + 8 * 4608);
      const f4a v9  = *(const f4a*)(b + 9 * 4608);
      const f4a v10 = *(const f4a*)(b + 10 * 4608);
      const f4a v11 = *(const f4a*)(b + 11 * 4608);
      const f4a v12 = *(const f4a*)(b + 12 * 4608);
      const f4a v13 = *(const f4a*)(b + 13 * 4608);
      const f4a v14 = *(const f4a*)(b + 14 * 4608);
      const f4a v15 = *(const f4a*)(b + 15 * 4608);
      const float w0 = wmb[rr + 0],  w1 = wmb[rr + 1];
      const float w2 = wmb[rr + 2],  w3 = wmb[rr + 3];
      const float w4 = wmb[rr + 4],  w5 = wmb[rr + 5];
      const float w6 = wmb[rr + 6],  w7 = wmb[rr + 7];
      const float w8 = wmb[rr + 8],  w9 = wmb[rr + 9];
      const float w10 = wmb[rr + 10], w11 = wmb[rr + 11];
      const float w12 = wmb[rr + 12], w13 = wmb[rr + 13];
      const float w14 = wmb[rr + 14], w15 = wmb[rr + 15];
      FMA4(w0, v0);   FMA4(w1, v1);   FMA4(w2, v2);   FMA4(w3, v3);
      FMA4(w4, v4);   FMA4(w5, v5);   FMA4(w6, v6);   FMA4(w7, v7);
      FMA4(w8, v8);   FMA4(w9, v9);   FMA4(w10, v10); FMA4(w11, v11);
      FMA4(w12, v12); FMA4(w13, v13); FMA4(w14, v14); FMA4(w15, v15);
    }
    __shared__ f4a red[128];
    if (rowg) red[colv] = acc;
    __syncthreads();
    if (!rowg) {
      const f4a o = red[colv];
      acc.x += o.x; acc.y += o.y; acc.z += o.z; acc.w += o.w;
      float* wp = ws + WS_WFP + (size_t)half * WFP_HALF + (size_t)g * 4608;
      *(f4a*)(wp + c0) = acc;
    }
  } else {
    // ---------------- CONV partials (VALU, hidden under fold) ----------------
    const int bid = bid0 - 2304;
    const int coblk = bid >> 7, pxblk = (bid >> 3) & 15, ks = bid & 7;
    const int ksub = tid >> 7, sub = tid & 127;
    const int cog = sub >> 5, pxg = sub & 31;
    const int row = pxg >> 4, x0 = (pxg & 15) * 2;
    const int y = pxblk * 2 + row;
    const int co0 = coblk * 16 + cog * 4;
    const int ci0 = ks * 64 + ksub * 32;
    const float* tfp = ws + WS_TFP;

    float acc[4][2] = {{0.f, 0.f}, {0.f, 0.f}, {0.f, 0.f}, {0.f, 0.f}};
    for (int i = 0; i < 32; i++) {
      const int ci = ci0 + i;
      const float* tin = tfp + (size_t)ci * 1156 + y * 34 + x0;
      const f4u p0 = *(const f4u*)(tin);
      const f4u p1 = *(const f4u*)(tin + 34);
      const f4u p2 = *(const f4u*)(tin + 68);
      #pragma unroll
      for (int c = 0; c < 4; c++) {
        const float* wr = wtgt + (size_t)(co0 + c) * 4608 + ci * 9;
        const f4u wa = *(const f4u*)(wr);
        const f4u wb = *(const f4u*)(wr + 4);
        const float w8 = wr[8];
        acc[c][0] += wa.x * p0.x + wa.y * p0.y + wa.z * p0.z
                   + wa.w * p1.x + wb.x * p1.y + wb.y * p1.z
                   + wb.z * p2.x + wb.w * p2.y + w8 * p2.z;
        acc[c][1] += wa.x * p0.y + wa.y * p0.z + wa.z * p0.w
                   + wa.w * p1.y + wb.x * p1.z + wb.y * p1.w
                   + wb.z * p2.y + wb.w * p2.z + w8 * p2.w;
      }
    }
    float* cvp = ws + WS_CVP + (size_t)(ks * 2 + ksub) * 262144;
    #pragma unroll
    for (int c = 0; c < 4; c++) {
      cvp[(co0 + c) * 1024 + y * 32 + x0 + 0] = acc[c][0];
      cvp[(co0 + c) * 1024 + y * 32 + x0 + 1] = acc[c][1];
    }
  }
}

__global__ __launch_bounds__(256) void K2_cred_z2(
    const float* __restrict__ btgt,
    const float* __restrict__ gamma, const float* __restrict__ beta,
    const float* __restrict__ mean, const float* __restrict__ var,
    const float* __restrict__ zfeat,    // template_feat 2*512*49
    float* ws)
{
  __shared__ float Tl[50][144];
  const int tid = threadIdx.x;
  if (blockIdx.x < 256) {
    // ---------------- cred: reduce CVP slabs + BN + 0.1 -> tP ----------------
    const int co = blockIdx.x;
    const float sc = gamma[co] * rsqrtf(var[co] + 1e-5f);
    const float off = btgt[co] - mean[co];
    const float bt = beta[co];
    const float* cvp = ws + WS_CVP + (size_t)co * 1024;
    float* tP = ws + WS_TP;
    #pragma unroll
    for (int k = 0; k < 4; k++) {
      const int j = k * 256 + tid;
      float s = 0.f;
      #pragma unroll
      for (int sl = 0; sl < 16; sl++) s += cvp[(size_t)sl * 262144 + j];
      const float t = ((s + off) * sc + bt) * 0.1f;
      const int yy = j >> 5, xx = j & 31;
      tP[co * 1520 + (yy + 3) * 40 + (xx + 3)] = t;
    }
  } else {
    // ---------------- z2 partials ----------------
    const int b2 = blockIdx.x - 256;
    const int n = b2 >> 5, kc = b2 & 31;
    const int ci0 = kc * 16;
    for (int idx = tid; idx < 7200; idx += 256) {
      const int uv = idx / 144, kk = idx % 144;
      float v = 0.f;
      if (uv < 49) {
        const int u = uv / 7, vv = uv % 7;
        const int ci = ci0 + kk / 9, pq = kk % 9;
        const int p = pq / 3, q = pq % 3;
        const int yy = u + p - 1, xx = vv + q - 1;
        if (yy >= 0 && yy < 7 && xx >= 0 && xx < 7)
          v = zfeat[n * 25088 + ci * 49 + yy * 7 + xx];
      }
      Tl[uv][kk] = v;
    }
    __syncthreads();
    const int ehq = tid & 31, uvg = tid >> 5;
    const int eh0 = ehq * 4;
    const int uv0 = (uvg == 0) ? 0 : uvg * 6 + 1;
    const float* wfp = ws + WS_WFP;
    float4 acc[7];
    #pragma unroll
    for (int i = 0; i < 7; i++) acc[i] = make_float4(0.f, 0.f, 0.f, 0.f);
    for (int g = 0; g < 36; g++) {
      const int koff = ci0 * 9 + g * 4;
      f4a wvE[4];
      #pragma unroll
      for (int e = 0; e < 4; e++) {
        const float* pe = wfp + (size_t)(eh0 + e) * 4608 + koff;
        f4a a = *(const f4a*)(pe);
        a += *(const f4a*)(pe + WFP_HALF);
        wvE[e] = a;
      }
      #pragma unroll
      for (int uu = 0; uu < 7; uu++) {
        const float4 t4 = *(const float4*)(&Tl[uv0 + uu][g * 4]);
        acc[uu].x = fmaf(t4.x, wvE[0].x, fmaf(t4.y, wvE[0].y, fmaf(t4.z, wvE[0].z, fmaf(t4.w, wvE[0].w, acc[uu].x))));
        acc[uu].y = fmaf(t4.x, wvE[1].x, fmaf(t4.y, wvE[1].y, fmaf(t4.z, wvE[1].z, fmaf(t4.w, wvE[1].w, acc[uu].y))));
        acc[uu].z = fmaf(t4.x, wvE[2].x, fmaf(t4.y, wvE[2].y, fmaf(t4.z, wvE[2].z, fmaf(t4.w, wvE[2].w, acc[uu].z))));
        acc[uu].w = fmaf(t4.x, wvE[3].x, fmaf(t4.y, wvE[3].y, fmaf(t4.z, wvE[3].z, fmaf(t4.w, wvE[3].w, acc[uu].w))));
      }
    }
    float* z2p = ws + WS_Z2P;
    #pragma unroll
    for (int uu = 0; uu < 7; uu++) {
      const int uv = uv0 + uu;
      if (uv <= 48)
        *(float4*)(z2p + ((size_t)((n * 32 + kc) * 49 + uv)) * 128 + eh0) = acc[uu];
    }
  }
}

__global__ __launch_bounds__(128) void k3_merged(float* ws)
{
  __shared__ float Z2s[16][7][8];
  const int tid = threadIdx.x;
  const int bid = blockIdx.x;
  const int n = bid >> 7, rest = bid & 127;
  const int ec = rest >> 4, hq = rest & 15;
  const int c0 = ec * 16, h0 = hq * 2;
  const float* z2p = ws + WS_Z2P;
  const float* bf = ws + WS_BF;
  for (int idx = tid; idx < 784; idx += 128) {
    const int cl = idx & 15, uv = idx >> 4;
    float s = bf[c0 + cl];
    const float* p = z2p + (size_t)(n * 1568 + uv) * 128 + (c0 + cl);
    #pragma unroll 8
    for (int kc = 0; kc < 32; kc++) s += p[(size_t)kc * 6272];
    Z2s[cl][uv / 7][uv % 7] = s;
  }
  for (int idx = tid; idx < 112; idx += 128)
    Z2s[idx / 7][idx % 7][7] = 0.f;
  __syncthreads();

  const int e = tid >> 4, row = (tid >> 3) & 1, wq = tid & 7;
  const int w0 = wq * 4;
  const float* tP = ws + WS_TP;
  float acc[4] = {0.f, 0.f, 0.f, 0.f};
  #pragma unroll
  for (int h128 = 0; h128 < 2; h128++) {
    const int cl = 2 * e + h128;
    const float* tc = tP + (size_t)(128 * n + c0 + cl) * 1520;
    #pragma unroll
    for (int u = 0; u < 7; u++) {
      const float* trow = tc + (h0 + row + u) * 40 + w0;
      float tw[12];
      *(float4*)&tw[0] = *(const float4*)(trow);
      *(float4*)&tw[4] = *(const float4*)(trow + 4);
      *(float4*)&tw[8] = *(const float4*)(trow + 8);
      float z[8];
      *(float4*)&z[0] = *(const float4*)&Z2s[cl][u][0];
      *(float4*)&z[4] = *(const float4*)&Z2s[cl][u][4];
      #pragma unroll
      for (int px = 0; px < 4; px++)
        #pragma unroll
        for (int v = 0; v < 8; v++)
          acc[px] = fmaf(z[v], tw[px + v], acc[px]);
    }
  }
  float* mrg = ws + WS_MRG;
  *(float4*)(mrg + (size_t)(((n * 64 + ec * 8 + e) * 32) + h0 + row) * 32 + w0) =
      make_float4(acc[0], acc[1], acc[2], acc[3]);
}

__global__ __launch_bounds__(256) void k4_heads(
    const float* __restrict__ cb,
    const float* __restrict__ wcls, const float* __restrict__ bcls,
    const float* __restrict__ wbox, const float* __restrict__ bbox,
    float* ws, float* __restrict__ out)
{
  __shared__ float mrg_l[32][66];
  __shared__ float wcb_l[54][64];
  __shared__ float bias_l[54];
  __shared__ float logits[18][32];
  const int tid = threadIdx.x;
  const int n = blockIdx.x >> 5, h = blockIdx.x & 31;
  const float* mrg = ws + WS_MRG;
  for (int idx = tid; idx < 2048; idx += 256) {
    const int e = idx >> 5, w = idx & 31;
    mrg_l[w][e] = mrg[(size_t)(((n * 64 + e) * 32) + h) * 32 + w] + cb[e];
  }
  for (int idx = tid; idx < 3456; idx += 256) {
    const int ch = idx >> 6, e = idx & 63;
    wcb_l[ch][e] = (ch < 18) ? wcls[ch * 64 + e] : wbox[(ch - 18) * 64 + e];
  }
  if (tid < 54) bias_l[tid] = (tid < 18) ? bcls[tid] : bbox[tid - 18];
  __syncthreads();

  const int w = tid & 31, chg = tid >> 5;
  const int cnt = (chg < 6) ? 7 : 6;
  float acc[7] = {0.f, 0.f, 0.f, 0.f, 0.f, 0.f, 0.f};
  for (int e2 = 0; e2 < 32; e2++) {
    const float2 m2 = *(const float2*)&mrg_l[w][e2 * 2];
    #pragma unroll
    for (int i = 0; i < 7; i++) {
      if (i < cnt) {
        const int ch = chg + 8 * i;
        const float2 wv = *(const float2*)&wcb_l[ch][e2 * 2];
        acc[i] = fmaf(m2.x, wv.x, acc[i]);
        acc[i] = fmaf(m2.y, wv.y, acc[i]);
      }
    }
  }
  #pragma unroll
  for (int i = 0; i < 7; i++) {
    if (i < cnt) {
      const int ch = chg + 8 * i;
      const float v = acc[i] + bias_l[ch];
      if (ch < 18) logits[ch][w] = v;
      else out[36864 + n * 36864 + (ch - 18) * 1024 + h * 32 + w] = v;
    }
  }
  __syncthreads();
  for (int idx = tid; idx < 576; idx += 256) {
    const int ch = idx >> 5, w2 = idx & 31;
    const float a = logits[ch][w2];
    const float b = logits[(ch + 9) % 18][w2];
    const float m = fmaxf(a, b);
    const float ea = expf(a - m), eb = expf(b - m);
    out[n * 18432 + ch * 1024 + h * 32 + w2] = ea / (ea + eb);
  }
}

extern "C" void kernel_launch(void* const* d_in, const int* in_sizes, int n_in,
                              void* d_out, int out_size, void* d_ws, size_t ws_size,
                              hipStream_t stream) {
  (void)in_sizes; (void)n_in; (void)out_size; (void)ws_size;
  const float* target_feat   = (const float*)d_in[0];
  const float* template_feat = (const float*)d_in[1];
  const float* w_target      = (const float*)d_in[2];
  const float* b_target      = (const float*)d_in[3];
  const float* bn_gamma      = (const float*)d_in[4];
  const float* bn_beta       = (const float*)d_in[5];
  const float* bn_mean       = (const float*)d_in[6];
  const float* bn_var        = (const float*)d_in[7];
  const float* w_template    = (const float*)d_in[8];
  const float* b_template    = (const float*)d_in[9];
  const float* w_merge       = (const float*)d_in[10];
  const float* corr_bias     = (const float*)d_in[11];
  const float* w_cls         = (const float*)d_in[12];
  const float* b_cls         = (const float*)d_in[13];
  const float* w_box         = (const float*)d_in[14];
  const float* b_box         = (const float*)d_in[15];
  float* ws = (float*)d_ws;
  float* out = (float*)d_out;

  hipLaunchKernelGGL(k0_prep, dim3(2048), dim3(256), 0, stream,
                     target_feat, w_merge, b_template, ws);
  hipLaunchKernelGGL(K1_fold_conv, dim3(4352), dim3(256), 0, stream,
                     w_template, w_merge, w_target, ws);
  hipLaunchKernelGGL(K2_cred_z2, dim3(320), dim3(256), 0, stream,
                     b_target, bn_gamma, bn_beta, bn_mean, bn_var,
                     template_feat, ws);
  hipLaunchKernelGGL(k3_merged, dim3(256), dim3(128), 0, stream, ws);
  hipLaunchKernelGGL(k4_heads, dim3(64), dim3(256), 0, stream,
                     corr_bias, w_cls, b_cls, w_box, b_box, ws, out);
}